// Round 3
// baseline (4530.225 us; speedup 1.0000x reference)
//
#include <hip/hip_runtime.h>
#include <hip/hip_bf16.h>

// StyleGAN2 modulated conv — FP32 variant (reference declares jnp.float32).
// b=16, c_in=256, c_out=256, h=w=64, k=3, style dim=512.
#define BATCH 16
#define CIN   256
#define COUT  256
#define HH    64
#define WW    64
#define SDIM  512
#define KK    9     // 3x3
#define NPIX  (HH*WW)   // 4096

// ---------------------------------------------------------------------------
// Kernel 1 (ws path): s[b][ci] = dot(w_style[b,:], aff_w[ci,:]) + aff_b[ci] + 1
// ---------------------------------------------------------------------------
__global__ __launch_bounds__(CIN) void style_kernel(
    const float* __restrict__ w_style,   // [BATCH][SDIM]
    const float* __restrict__ aff_w,     // [CIN][SDIM]
    const float* __restrict__ aff_b,     // [CIN]
    float* __restrict__ s)               // [BATCH][CIN]
{
    const int b = blockIdx.x;
    const int c = threadIdx.x;
    const float* ws = w_style + b * SDIM;
    const float* aw = aff_w + c * SDIM;
    float acc = 0.f;
#pragma unroll 8
    for (int j = 0; j < SDIM; ++j)
        acc += ws[j] * aw[j];
    s[b * CIN + c] = acc + aff_b[c] + 1.0f;
}

// ---------------------------------------------------------------------------
// Fused kernel: per-block (b,co) modulation + demodulation + direct 3x3 conv.
// grid = (BATCH*COUT, NPIX/256); block = 256 threads, one output pixel each.
// LDS: 2304 fp32 normalized weights (9.2 KB) + 1 KB reduction scratch.
// ---------------------------------------------------------------------------
template <bool FUSE_S>
__global__ __launch_bounds__(256) void conv_mod_kernel(
    const float* __restrict__ x,         // [BATCH][CIN][HH][WW]
    const float* __restrict__ W,         // [COUT][CIN][KK]
    const float* __restrict__ s_pre,     // [BATCH][CIN] (ws path) or nullptr
    const float* __restrict__ w_style,   // [BATCH][SDIM]
    const float* __restrict__ aff_w,     // [CIN][SDIM]
    const float* __restrict__ aff_b,     // [CIN]
    float* __restrict__ out)             // [BATCH][COUT][HH][WW]
{
    const int bc  = blockIdx.x;          // b*COUT + co
    const int b   = bc >> 8;
    const int co  = bc & 255;
    const int tid = threadIdx.x;         // = ci for steps 1-2

    __shared__ float wsh[CIN * KK];      // normalized fp32 weights
    __shared__ float red[CIN];

    // --- step 1: per-input-channel style scale sv = s[b][tid] ---
    float sv;
    if (FUSE_S) {
        __shared__ float wst[SDIM];
        for (int j = tid; j < SDIM; j += 256) wst[j] = w_style[b * SDIM + j];
        __syncthreads();
        const float* aw = aff_w + tid * SDIM;
        float acc = 0.f;
#pragma unroll 8
        for (int j = 0; j < SDIM; ++j)
            acc += wst[j] * aw[j];
        sv = acc + aff_b[tid] + 1.0f;
    } else {
        sv = s_pre[b * CIN + tid];
    }

    // --- step 2: modulate W[co][tid][:], block-reduce for demod, stage in LDS ---
    {
        const float* wp = W + (co * CIN + tid) * KK;
        float m[KK];
        float part = 0.f;
#pragma unroll
        for (int r = 0; r < KK; ++r) {
            m[r] = wp[r] * sv;
            part += m[r] * m[r];
        }
        red[tid] = part;
        __syncthreads();
#pragma unroll
        for (int off = CIN / 2; off > 0; off >>= 1) {
            if (tid < off) red[tid] += red[tid + off];
            __syncthreads();
        }
        const float d = rsqrtf(red[0] + 1e-8f);
#pragma unroll
        for (int r = 0; r < KK; ++r)
            wsh[tid * KK + r] = m[r] * d;
        __syncthreads();
    }

    // --- step 3: direct conv, one pixel per thread ---
    const int p  = blockIdx.y * 256 + tid;   // 0..4095
    const int y  = p >> 6;
    const int xx = p & 63;

    const bool vt = (y > 0), vb = (y < HH - 1);
    const bool vl = (xx > 0), vr = (xx < WW - 1);
    const bool val[KK] = { vt && vl, vt, vt && vr,
                           vl,       true, vr,
                           vb && vl, vb, vb && vr };
    const int off9[KK] = { -WW - 1, -WW, -WW + 1,
                           -1,       0,   1,
                            WW - 1,  WW,  WW + 1 };

    const float* xb = x + (size_t)b * CIN * NPIX + p;

    float acc = 0.f;
    for (int ci = 0; ci < CIN; ++ci) {
        const float* xp = xb + ci * NPIX;
        const float* wp = wsh + ci * KK;
#pragma unroll
        for (int r = 0; r < KK; ++r) {
            const float xv = val[r] ? xp[off9[r]] : 0.f;
            acc += xv * wp[r];
        }
    }
    out[(size_t)bc * NPIX + p] = acc;
}

// ---------------------------------------------------------------------------
extern "C" void kernel_launch(void* const* d_in, const int* in_sizes, int n_in,
                              void* d_out, int out_size, void* d_ws, size_t ws_size,
                              hipStream_t stream) {
    const float* x       = (const float*)d_in[0];   // 16*256*64*64
    const float* w_style = (const float*)d_in[1];   // 16*512
    const float* W       = (const float*)d_in[2];   // 256*256*3*3
    const float* aff_w   = (const float*)d_in[3];   // 256*512
    const float* aff_b   = (const float*)d_in[4];   // 256
    float* out = (float*)d_out;

    const dim3 grid(BATCH * COUT, NPIX / 256);
    const dim3 blk(256);

    if (ws_size >= (size_t)(BATCH * CIN * sizeof(float))) {
        float* s = (float*)d_ws;
        style_kernel<<<dim3(BATCH), dim3(CIN), 0, stream>>>(w_style, aff_w, aff_b, s);
        conv_mod_kernel<false><<<grid, blk, 0, stream>>>(x, W, s, w_style, aff_w, aff_b, out);
    } else {
        conv_mod_kernel<true><<<grid, blk, 0, stream>>>(x, W, nullptr, w_style, aff_w, aff_b, out);
    }
}

// Round 4
// 251.203 us; speedup vs baseline: 18.0341x; 18.0341x over previous
//
#include <hip/hip_runtime.h>
#include <hip/hip_bf16.h>

// StyleGAN2 modulated conv, fp32 in/out, bf16 MFMA implicit GEMM (NHWC).
// b=16, c_in=256, c_out=256, h=w=64, k=3.
#define BATCH 16
#define CIN   256
#define COUT  256
#define HH    64
#define WW    64
#define SDIM  512
#define NPIX  4096
#define PADH  66            // 64 + halo row each side
#define PADW  66

typedef __hip_bfloat16 bf16;
typedef __attribute__((ext_vector_type(8))) short short8;   // 8 bf16 (4 VGPR)
typedef __attribute__((ext_vector_type(4))) float f32x4;

__device__ __forceinline__ void glds16(const void* g, void* l) {
    __builtin_amdgcn_global_load_lds(
        (const __attribute__((address_space(1))) unsigned int*)g,
        (__attribute__((address_space(3))) unsigned int*)l, 16, 0, 0);
}

// ---------------------------------------------------------------------------
// P1: s[b][ci] = dot(w_style[b,:], aff_w[ci,:]) + aff_b[ci] + 1
// ---------------------------------------------------------------------------
__global__ __launch_bounds__(CIN) void style_kernel(
    const float* __restrict__ w_style, const float* __restrict__ aff_w,
    const float* __restrict__ aff_b, float* __restrict__ s)
{
    const int b = blockIdx.x, c = threadIdx.x;
    const float* ws = w_style + b * SDIM;
    const float* aw = aff_w + c * SDIM;
    float acc = 0.f;
#pragma unroll 8
    for (int j = 0; j < SDIM; ++j) acc += ws[j] * aw[j];
    s[b * CIN + c] = acc + aff_b[c] + 1.0f;
}

// ---------------------------------------------------------------------------
// P2: modulate + demodulate, write bf16 transposed: wt[b][r][co][ci]
// block per (b,co), thread = ci.
// ---------------------------------------------------------------------------
__global__ __launch_bounds__(CIN) void wgt_kernel(
    const float* __restrict__ W, const float* __restrict__ s,
    bf16* __restrict__ wt)
{
    const int bc = blockIdx.x, b = bc >> 8, co = bc & 255, ci = threadIdx.x;
    const float* wp = W + (co * CIN + ci) * 9;
    const float sv = s[b * CIN + ci];
    float m[9], part = 0.f;
#pragma unroll
    for (int r = 0; r < 9; ++r) { m[r] = wp[r] * sv; part += m[r] * m[r]; }
    __shared__ float red[CIN];
    red[ci] = part;
    __syncthreads();
#pragma unroll
    for (int off = CIN / 2; off > 0; off >>= 1) {
        if (ci < off) red[ci] += red[ci + off];
        __syncthreads();
    }
    const float d = rsqrtf(red[0] + 1e-8f);
#pragma unroll
    for (int r = 0; r < 9; ++r)
        wt[(((size_t)b * 9 + r) * COUT + co) * CIN + ci] = __float2bfloat16(m[r] * d);
}

// ---------------------------------------------------------------------------
// P3: x [b][ci][64][64] fp32  ->  xt [b][66][66][ci] bf16 with zero halo.
// grid (66, 16): one padded row per block.  LDS transpose, +2 pad on ci to
// keep the col-strided write phase 2-way (free) on banks.
// ---------------------------------------------------------------------------
__global__ __launch_bounds__(256) void xpose_kernel(
    const float* __restrict__ x, bf16* __restrict__ xt)
{
    const int row = blockIdx.x, b = blockIdx.y, tid = threadIdx.x;
    bf16* orow = xt + (((size_t)b * PADH + row) * PADW) * CIN;

    if (row == 0 || row == PADH - 1) {
        uint4 z = {0, 0, 0, 0};
        for (int i = tid; i < PADW * CIN / 8; i += 256) ((uint4*)orow)[i] = z;
        return;
    }
    __shared__ bf16 t[64][CIN + 2];
    const float* xr = x + ((size_t)b * CIN * NPIX) + (row - 1) * WW;
    for (int i = tid; i < CIN * WW; i += 256) {          // coalesced 64-f rows
        const int ci = i >> 6, col = i & 63;
        t[col][ci] = __float2bfloat16(xr[(size_t)ci * NPIX + col]);
    }
    __syncthreads();
    const bf16 z16 = __float2bfloat16(0.f);
    for (int i = tid; i < PADW * CIN; i += 256) {        // coalesced writes
        const int col = i >> 8, ci = i & 255;
        orow[i] = (col == 0 || col == PADW - 1) ? z16 : t[col - 1][ci];
    }
}

// ---------------------------------------------------------------------------
// GEMM: out[b][co][px] = sum_{r,ci} wt[b][r][co][ci] * xt[b][y+dy+1][x+dx+1][ci]
// Tile 128co x 128px (2 image rows), 4 waves, 4x4 mfma_f32_16x16x32_bf16 each.
// B-tile (x + halo) staged once per 64-ci block, shared by all 9 taps.
// ---------------------------------------------------------------------------
__global__ __launch_bounds__(256) void gemm_kernel(
    const bf16* __restrict__ xt,   // [B][66][66][256]
    const bf16* __restrict__ wt,   // [B][9][256][256]
    float* __restrict__ out)       // [B][256][4096]
{
    const int bid = blockIdx.x;
    const int b  = bid >> 6;
    const int mt = (bid >> 5) & 1;
    const int nt = bid & 31;
    const int tid  = threadIdx.x;
    const int wave = tid >> 6, lane = tid & 63;
    const int wm = wave >> 1, wn = wave & 1;
    const int lm = lane & 15, quad = lane >> 4;

    __shared__ bf16 Ash[128 * 64];           // [co][ci]    16 KB
    __shared__ bf16 Bsh[4 * PADW * 64];      // [row][col][ci]  33 KB

    f32x4 acc[4][4] = {};

    const int y0 = nt * 2;                                   // padded-row base
    const bf16* xb = xt + (size_t)b * PADH * PADW * CIN;
    const bf16* wb = wt + ((size_t)b * 9) * COUT * CIN + (size_t)mt * 128 * CIN;

    // B-fragment pixel decomposition (per n-tile), constant across k
    int pyl[4], pxx[4];
#pragma unroll
    for (int ni = 0; ni < 4; ++ni) {
        const int px = wn * 64 + ni * 16 + lm;
        pyl[ni] = px >> 6; pxx[ni] = px & 63;
    }

    for (int ci0 = 0; ci0 < CIN; ci0 += 64) {
        __syncthreads();
        // stage B: 4 rows x 66 cols x 64 ci  (2112 x 16B chunks)
        for (int i = tid; i < 4 * PADW * 8; i += 256) {
            const int row = i / (PADW * 8);
            const int j   = i - row * (PADW * 8);
            const int col = j >> 3, c8 = j & 7;
            glds16(xb + (((y0 + row) * PADW + col) * CIN + ci0 + c8 * 8),
                   Bsh + i * 8);
        }
#pragma unroll 1
        for (int r = 0; r < 9; ++r) {
            if (r) __syncthreads();
            // stage A: 128 co x 64 ci (1024 x 16B chunks)
            const bf16* wr = wb + r * (COUT * CIN) + ci0;
            for (int i = tid; i < 1024; i += 256) {
                const int co = i >> 3, c8 = i & 7;
                glds16(wr + co * CIN + c8 * 8, Ash + i * 8);
            }
            __syncthreads();

            const int dy = r / 3 - 1, dx = r % 3 - 1;
#pragma unroll
            for (int kk = 0; kk < 2; ++kk) {
                short8 af[4], bfr[4];
#pragma unroll
                for (int mi = 0; mi < 4; ++mi)
                    af[mi] = *(const short8*)(Ash + (wm * 64 + mi * 16 + lm) * 64
                                              + kk * 32 + quad * 8);
#pragma unroll
                for (int ni = 0; ni < 4; ++ni) {
                    const int rrow = 1 + pyl[ni] + dy;
                    const int ccol = pxx[ni] + 1 + dx;
                    bfr[ni] = *(const short8*)(Bsh + (rrow * PADW + ccol) * 64
                                               + kk * 32 + quad * 8);
                }
#pragma unroll
                for (int mi = 0; mi < 4; ++mi)
#pragma unroll
                    for (int ni = 0; ni < 4; ++ni)
                        acc[mi][ni] = __builtin_amdgcn_mfma_f32_16x16x32_bf16(
                            af[mi], bfr[ni], acc[mi][ni], 0, 0, 0);
            }
        }
    }

    // epilogue: C/D layout col=lane&15 (px), row=quad*4+v (co)
    float* ob = out + (size_t)b * COUT * NPIX + (size_t)mt * 128 * NPIX + nt * 128;
#pragma unroll
    for (int mi = 0; mi < 4; ++mi) {
        const int cl = wm * 64 + mi * 16 + quad * 4;
#pragma unroll
        for (int ni = 0; ni < 4; ++ni) {
            const int px = wn * 64 + ni * 16 + lm;
#pragma unroll
            for (int v = 0; v < 4; ++v)
                ob[(size_t)(cl + v) * NPIX + px] = acc[mi][ni][v];
        }
    }
}

// ---------------------------------------------------------------------------
// Fallback (round-2, known correct) for small workspace.
// ---------------------------------------------------------------------------
template <bool FUSE_S>
__global__ __launch_bounds__(256) void conv_mod_kernel(
    const float* __restrict__ x, const float* __restrict__ W,
    const float* __restrict__ s_pre, const float* __restrict__ w_style,
    const float* __restrict__ aff_w, const float* __restrict__ aff_b,
    float* __restrict__ out)
{
    const int bc = blockIdx.x, b = bc >> 8, co = bc & 255, tid = threadIdx.x;
    __shared__ float wsh[CIN * 9];
    __shared__ float red[CIN];
    float sv;
    if (FUSE_S) {
        __shared__ float wst[SDIM];
        for (int j = tid; j < SDIM; j += 256) wst[j] = w_style[b * SDIM + j];
        __syncthreads();
        const float* aw = aff_w + tid * SDIM;
        float a2 = 0.f;
#pragma unroll 8
        for (int j = 0; j < SDIM; ++j) a2 += wst[j] * aw[j];
        sv = a2 + aff_b[tid] + 1.0f;
    } else sv = s_pre[b * CIN + tid];
    {
        const float* wp = W + (co * CIN + tid) * 9;
        float m[9], part = 0.f;
#pragma unroll
        for (int r = 0; r < 9; ++r) { m[r] = wp[r] * sv; part += m[r] * m[r]; }
        red[tid] = part;
        __syncthreads();
#pragma unroll
        for (int off = CIN / 2; off > 0; off >>= 1) {
            if (tid < off) red[tid] += red[tid + off];
            __syncthreads();
        }
        const float d = rsqrtf(red[0] + 1e-8f);
#pragma unroll
        for (int r = 0; r < 9; ++r) wsh[tid * 9 + r] = m[r] * d;
        __syncthreads();
    }
    const int p = blockIdx.y * 256 + tid, y = p >> 6, xx = p & 63;
    const bool vt = y > 0, vb = y < HH - 1, vl = xx > 0, vr = xx < WW - 1;
    const bool val[9] = { vt && vl, vt, vt && vr, vl, true, vr, vb && vl, vb, vb && vr };
    const int off9[9] = { -WW - 1, -WW, -WW + 1, -1, 0, 1, WW - 1, WW, WW + 1 };
    const float* xbp = x + (size_t)b * CIN * NPIX + p;
    float acc = 0.f;
    for (int ci = 0; ci < CIN; ++ci) {
        const float* xp = xbp + ci * NPIX;
        const float* wp = wsh + ci * 9;
#pragma unroll
        for (int r = 0; r < 9; ++r) acc += (val[r] ? xp[off9[r]] : 0.f) * wp[r];
    }
    out[(size_t)bc * NPIX + p] = acc;
}

// ---------------------------------------------------------------------------
extern "C" void kernel_launch(void* const* d_in, const int* in_sizes, int n_in,
                              void* d_out, int out_size, void* d_ws, size_t ws_size,
                              hipStream_t stream) {
    const float* x       = (const float*)d_in[0];
    const float* w_style = (const float*)d_in[1];
    const float* W       = (const float*)d_in[2];
    const float* aff_w   = (const float*)d_in[3];
    const float* aff_b   = (const float*)d_in[4];
    float* out = (float*)d_out;

    const size_t s_off   = 0;
    const size_t wt_off  = 65536;
    const size_t wt_sz   = (size_t)BATCH * 9 * COUT * CIN * sizeof(bf16);   // 18.9 MB
    const size_t xt_off  = wt_off + wt_sz;
    const size_t xt_sz   = (size_t)BATCH * PADH * PADW * CIN * sizeof(bf16); // 35.7 MB
    const size_t need    = xt_off + xt_sz;

    if (ws_size >= need) {
        float* s  = (float*)((char*)d_ws + s_off);
        bf16* wt  = (bf16*)((char*)d_ws + wt_off);
        bf16* xt  = (bf16*)((char*)d_ws + xt_off);
        style_kernel<<<dim3(BATCH), dim3(CIN), 0, stream>>>(w_style, aff_w, aff_b, s);
        wgt_kernel<<<dim3(BATCH * COUT), dim3(CIN), 0, stream>>>(W, s, wt);
        xpose_kernel<<<dim3(PADH, BATCH), dim3(256), 0, stream>>>(x, xt);
        gemm_kernel<<<dim3(BATCH * 64), dim3(256), 0, stream>>>(xt, wt, out);
    } else if (ws_size >= (size_t)(BATCH * CIN * sizeof(float))) {
        float* s = (float*)d_ws;
        style_kernel<<<dim3(BATCH), dim3(CIN), 0, stream>>>(w_style, aff_w, aff_b, s);
        conv_mod_kernel<false><<<dim3(BATCH * COUT, NPIX / 256), dim3(256), 0, stream>>>(
            x, W, s, w_style, aff_w, aff_b, out);
    } else {
        conv_mod_kernel<true><<<dim3(BATCH * COUT, NPIX / 256), dim3(256), 0, stream>>>(
            x, W, nullptr, w_style, aff_w, aff_b, out);
    }
}

// Round 5
// 229.571 us; speedup vs baseline: 19.7334x; 1.0942x over previous
//
#include <hip/hip_runtime.h>
#include <hip/hip_bf16.h>

// StyleGAN2 modulated conv, fp32 in/out, bf16 MFMA implicit GEMM (NHWC).
// b=16, c_in=256, c_out=256, h=w=64, k=3.
#define BATCH 16
#define CIN   256
#define COUT  256
#define HH    64
#define WW    64
#define SDIM  512
#define NPIX  4096
#define PADH  66
#define PADW  66

typedef __hip_bfloat16 bf16;
typedef __attribute__((ext_vector_type(8))) short short8;   // 8 bf16
typedef __attribute__((ext_vector_type(4))) float f32x4;

__device__ __forceinline__ void glds16(const void* g, void* l) {
    __builtin_amdgcn_global_load_lds(
        (const __attribute__((address_space(1))) unsigned int*)g,
        (__attribute__((address_space(3))) unsigned int*)l, 16, 0, 0);
}

// ---------------------------------------------------------------------------
// P1: s[b][ci] = dot(w_style[b,:], aff_w[ci,:]) + aff_b[ci] + 1
// ---------------------------------------------------------------------------
__global__ __launch_bounds__(256) void style_kernel(
    const float* __restrict__ w_style, const float* __restrict__ aff_w,
    const float* __restrict__ aff_b, float* __restrict__ s)
{
    const int b = blockIdx.x, c = threadIdx.x;
    __shared__ float ws[SDIM];
    for (int j = c; j < SDIM; j += 256) ws[j] = w_style[b * SDIM + j];
    __syncthreads();
    const float* aw = aff_w + (size_t)c * SDIM;
    float acc = 0.f;
#pragma unroll 4
    for (int j = 0; j < SDIM; j += 4) {
        const float4 a = *(const float4*)(aw + j);
        acc += a.x * ws[j] + a.y * ws[j + 1] + a.z * ws[j + 2] + a.w * ws[j + 3];
    }
    s[b * CIN + c] = acc + aff_b[c] + 1.0f;
}

// ---------------------------------------------------------------------------
// P2 fused: blocks [0,4096) = weight mod/demod -> wt[b][r][co][ci] bf16
//           blocks [4096,5152) = x NCHW fp32 -> xt[b][66][66][ci] bf16 (zero halo)
// ---------------------------------------------------------------------------
__global__ __launch_bounds__(256) void prep_kernel(
    const float* __restrict__ W, const float* __restrict__ s,
    const float* __restrict__ x,
    bf16* __restrict__ wt, bf16* __restrict__ xt)
{
    __shared__ union {
        float wl[CIN * 9];          // 9.2 KB (wgt part)
        bf16  t[WW][CIN + 2];       // 33 KB  (xpose part)
        float red4[4];
    } sh;
    const int tid = threadIdx.x;

    if (blockIdx.x < BATCH * COUT) {
        // ---- weight branch: one block per (b,co) ----
        const int bc = blockIdx.x, b = bc >> 8, co = bc & 255, ci = tid;
        const float* wrow = W + (size_t)co * (CIN * 9);
        for (int i = ci; i < CIN * 9 / 4; i += 256)
            *(float4*)&sh.wl[i * 4] = *(const float4*)(wrow + i * 4);
        __syncthreads();
        const float sv = s[b * CIN + ci];
        float m[9], part = 0.f;
#pragma unroll
        for (int r = 0; r < 9; ++r) { m[r] = sh.wl[ci * 9 + r] * sv; part += m[r] * m[r]; }
#pragma unroll
        for (int off = 32; off > 0; off >>= 1)
            part += __shfl_down(part, off, 64);
        __syncthreads();                    // protect union before re-use
        __shared__ float red[4];
        if ((ci & 63) == 0) red[ci >> 6] = part;
        __syncthreads();
        const float d = rsqrtf(red[0] + red[1] + red[2] + red[3] + 1e-8f);
#pragma unroll
        for (int r = 0; r < 9; ++r)
            wt[(((size_t)b * 9 + r) * COUT + co) * CIN + ci] = __float2bfloat16(m[r] * d);
    } else {
        // ---- transpose branch: one block per padded row ----
        const int xb  = blockIdx.x - BATCH * COUT;
        const int row = xb % PADH, b = xb / PADH;
        bf16* orow = xt + (((size_t)b * PADH + row) * PADW) * CIN;

        if (row == 0 || row == PADH - 1) {
            const uint4 z = {0, 0, 0, 0};
            for (int i = tid; i < PADW * CIN / 8; i += 256) ((uint4*)orow)[i] = z;
            return;
        }
        const float* xr = x + ((size_t)b * CIN * NPIX) + (size_t)(row - 1) * WW;
        // phase 1: float4 coalesced reads, transpose into LDS (stride 258 -> 2-way)
        for (int i = tid; i < CIN * (WW / 4); i += 256) {
            const int ci = i >> 4, c4 = (i & 15) * 4;
            const float4 v = *(const float4*)(xr + (size_t)ci * NPIX + c4);
            sh.t[c4 + 0][ci] = __float2bfloat16(v.x);
            sh.t[c4 + 1][ci] = __float2bfloat16(v.y);
            sh.t[c4 + 2][ci] = __float2bfloat16(v.z);
            sh.t[c4 + 3][ci] = __float2bfloat16(v.w);
        }
        __syncthreads();
        // phase 2: 8 bf16 per thread, uint4 global stores
        for (int i = tid; i < PADW * (CIN / 8); i += 256) {
            const int col = i >> 5, c8 = (i & 31) * 8;
            uint4 v = {0, 0, 0, 0};
            if (col > 0 && col < PADW - 1) {
                const unsigned* tp = (const unsigned*)&sh.t[col - 1][c8]; // 4B-aligned
                v.x = tp[0]; v.y = tp[1]; v.z = tp[2]; v.w = tp[3];
            }
            ((uint4*)orow)[i] = v;
        }
    }
}

// ---------------------------------------------------------------------------
// GEMM: out[b][co][px] = sum_{r,ci} wt[b][r][co][ci] * xt[b][y+dy+1][x+dx+1][ci]
// 128co x 128px tiles, 4 waves, 4x4 mfma_f32_16x16x32_bf16.
// XOR-swizzled LDS (16B chunk ^ (row&7)); inverse permutation applied on the
// global source of global_load_lds so lane->LDS stays contiguous.
// ---------------------------------------------------------------------------
__global__ __launch_bounds__(256) void gemm_kernel(
    const bf16* __restrict__ xt,   // [B][66][66][256]
    const bf16* __restrict__ wt,   // [B][9][256][256]
    float* __restrict__ out)       // [B][256][4096]
{
    const int bid = blockIdx.x;
    const int b  = bid >> 6;
    const int mt = (bid >> 5) & 1;
    const int nt = bid & 31;
    const int tid  = threadIdx.x;
    const int wave = tid >> 6, lane = tid & 63;
    const int wm = wave >> 1, wn = wave & 1;
    const int lm = lane & 15, quad = lane >> 4;

    __shared__ bf16 Ash[128 * 64];           // [co][ci] swizzled, 16 KB
    __shared__ bf16 Bsh[4 * PADW * 64];      // [pix][ci] swizzled, 33 KB

    f32x4 acc[4][4] = {};

    const int y0 = nt * 2;
    const bf16* xb = xt + (size_t)b * PADH * PADW * CIN;
    const bf16* wb = wt + ((size_t)b * 9) * COUT * CIN + (size_t)mt * 128 * CIN;

    int pyl[4], pxx[4];
#pragma unroll
    for (int ni = 0; ni < 4; ++ni) {
        const int px = wn * 64 + ni * 16 + lm;
        pyl[ni] = px >> 6; pxx[ni] = px & 63;
    }

    for (int ci0 = 0; ci0 < CIN; ci0 += 64) {
        __syncthreads();
        // stage B: 4 rows x 66 cols x 64 ci; source chunk = pc ^ (pix&7)
        for (int i = tid; i < 4 * PADW * 8; i += 256) {
            const int row = i / (PADW * 8);
            const int j   = i - row * (PADW * 8);
            const int col = j >> 3, pc = j & 7;
            const int p   = row * PADW + col;
            const int lc  = pc ^ (p & 7);
            glds16(xb + (((size_t)(y0 + row) * PADW + col) * CIN + ci0 + lc * 8),
                   Bsh + i * 8);
        }
#pragma unroll 1
        for (int r = 0; r < 9; ++r) {
            if (r) __syncthreads();
            // stage A: 128 co x 64 ci; source chunk = pc ^ (co&7)
            const bf16* wr = wb + r * (COUT * CIN) + ci0;
            for (int i = tid; i < 1024; i += 256) {
                const int co = i >> 3, pc = i & 7;
                const int lc = pc ^ (co & 7);
                glds16(wr + co * CIN + lc * 8, Ash + i * 8);
            }
            __syncthreads();

            const int dy = r / 3 - 1, dx = r % 3 - 1;
#pragma unroll
            for (int kk = 0; kk < 2; ++kk) {
                short8 af[4], bfr[4];
#pragma unroll
                for (int mi = 0; mi < 4; ++mi) {
                    const int arow = wm * 64 + mi * 16 + lm;
                    const int lc   = kk * 4 + quad;
                    af[mi] = *(const short8*)(Ash + arow * 64
                                              + (lc ^ (arow & 7)) * 8);
                }
#pragma unroll
                for (int ni = 0; ni < 4; ++ni) {
                    const int p  = (1 + pyl[ni] + dy) * PADW + pxx[ni] + 1 + dx;
                    const int lc = kk * 4 + quad;
                    bfr[ni] = *(const short8*)(Bsh + p * 64
                                               + (lc ^ (p & 7)) * 8);
                }
#pragma unroll
                for (int mi = 0; mi < 4; ++mi)
#pragma unroll
                    for (int ni = 0; ni < 4; ++ni)
                        acc[mi][ni] = __builtin_amdgcn_mfma_f32_16x16x32_bf16(
                            af[mi], bfr[ni], acc[mi][ni], 0, 0, 0);
            }
        }
    }

    // epilogue: C/D layout col=lane&15 (px), row=quad*4+v (co)
    float* ob = out + (size_t)b * COUT * NPIX + (size_t)mt * 128 * NPIX + nt * 128;
#pragma unroll
    for (int mi = 0; mi < 4; ++mi) {
        const int cl = wm * 64 + mi * 16 + quad * 4;
#pragma unroll
        for (int ni = 0; ni < 4; ++ni) {
            const int px = wn * 64 + ni * 16 + lm;
#pragma unroll
            for (int v = 0; v < 4; ++v)
                ob[(size_t)(cl + v) * NPIX + px] = acc[mi][ni][v];
        }
    }
}

// ---------------------------------------------------------------------------
// Fallback (round-2, known correct) for small workspace.
// ---------------------------------------------------------------------------
template <bool FUSE_S>
__global__ __launch_bounds__(256) void conv_mod_kernel(
    const float* __restrict__ x, const float* __restrict__ W,
    const float* __restrict__ s_pre, const float* __restrict__ w_style,
    const float* __restrict__ aff_w, const float* __restrict__ aff_b,
    float* __restrict__ out)
{
    const int bc = blockIdx.x, b = bc >> 8, co = bc & 255, tid = threadIdx.x;
    __shared__ float wsh[CIN * 9];
    __shared__ float red[CIN];
    float sv;
    if (FUSE_S) {
        __shared__ float wst[SDIM];
        for (int j = tid; j < SDIM; j += 256) wst[j] = w_style[b * SDIM + j];
        __syncthreads();
        const float* aw = aff_w + tid * SDIM;
        float a2 = 0.f;
#pragma unroll 8
        for (int j = 0; j < SDIM; ++j) a2 += wst[j] * aw[j];
        sv = a2 + aff_b[tid] + 1.0f;
    } else sv = s_pre[b * CIN + tid];
    {
        const float* wp = W + (co * CIN + tid) * 9;
        float m[9], part = 0.f;
#pragma unroll
        for (int r = 0; r < 9; ++r) { m[r] = wp[r] * sv; part += m[r] * m[r]; }
        red[tid] = part;
        __syncthreads();
#pragma unroll
        for (int off = CIN / 2; off > 0; off >>= 1) {
            if (tid < off) red[tid] += red[tid + off];
            __syncthreads();
        }
        const float d = rsqrtf(red[0] + 1e-8f);
#pragma unroll
        for (int r = 0; r < 9; ++r) wsh[tid * 9 + r] = m[r] * d;
        __syncthreads();
    }
    const int p = blockIdx.y * 256 + tid, y = p >> 6, xx = p & 63;
    const bool vt = y > 0, vb = y < HH - 1, vl = xx > 0, vr = xx < WW - 1;
    const bool val[9] = { vt && vl, vt, vt && vr, vl, true, vr, vb && vl, vb, vb && vr };
    const int off9[9] = { -WW - 1, -WW, -WW + 1, -1, 0, 1, WW - 1, WW, WW + 1 };
    const float* xbp = x + (size_t)b * CIN * NPIX + p;
    float acc = 0.f;
    for (int ci = 0; ci < CIN; ++ci) {
        const float* xp = xbp + ci * NPIX;
        const float* wp = wsh + ci * 9;
#pragma unroll
        for (int r = 0; r < 9; ++r) acc += (val[r] ? xp[off9[r]] : 0.f) * wp[r];
    }
    out[(size_t)bc * NPIX + p] = acc;
}

// ---------------------------------------------------------------------------
extern "C" void kernel_launch(void* const* d_in, const int* in_sizes, int n_in,
                              void* d_out, int out_size, void* d_ws, size_t ws_size,
                              hipStream_t stream) {
    const float* x       = (const float*)d_in[0];
    const float* w_style = (const float*)d_in[1];
    const float* W       = (const float*)d_in[2];
    const float* aff_w   = (const float*)d_in[3];
    const float* aff_b   = (const float*)d_in[4];
    float* out = (float*)d_out;

    const size_t wt_off  = 65536;
    const size_t wt_sz   = (size_t)BATCH * 9 * COUT * CIN * sizeof(bf16);
    const size_t xt_off  = wt_off + wt_sz;
    const size_t xt_sz   = (size_t)BATCH * PADH * PADW * CIN * sizeof(bf16);
    const size_t need    = xt_off + xt_sz;

    if (ws_size >= need) {
        float* s  = (float*)d_ws;
        bf16* wt  = (bf16*)((char*)d_ws + wt_off);
        bf16* xt  = (bf16*)((char*)d_ws + xt_off);
        style_kernel<<<dim3(BATCH), dim3(256), 0, stream>>>(w_style, aff_w, aff_b, s);
        prep_kernel<<<dim3(BATCH * COUT + BATCH * PADH), dim3(256), 0, stream>>>(
            W, s, x, wt, xt);
        gemm_kernel<<<dim3(BATCH * 64), dim3(256), 0, stream>>>(xt, wt, out);
    } else if (ws_size >= (size_t)(BATCH * CIN * sizeof(float))) {
        float* s = (float*)d_ws;
        style_kernel<<<dim3(BATCH), dim3(256), 0, stream>>>(w_style, aff_w, aff_b, s);
        conv_mod_kernel<false><<<dim3(BATCH * COUT, NPIX / 256), dim3(256), 0, stream>>>(
            x, W, s, w_style, aff_w, aff_b, out);
    } else {
        conv_mod_kernel<true><<<dim3(BATCH * COUT, NPIX / 256), dim3(256), 0, stream>>>(
            x, W, nullptr, w_style, aff_w, aff_b, out);
    }
}